// Round 1
// baseline (719.057 us; speedup 1.0000x reference)
//
#include <hip/hip_runtime.h>

typedef __attribute__((ext_vector_type(8))) short bfrag;
typedef __attribute__((ext_vector_type(4))) float f32x4;

#define SA 80  // LDS row stride in bf16 elements (64 + 16 pad: keeps 16B align, spreads banks)

__device__ __forceinline__ short f2bf(float f) {
  union { float f; unsigned u; } v; v.f = f;
  unsigned r = v.u + 0x7FFFu + ((v.u >> 16) & 1u);  // RNE
  return (short)(r >> 16);
}
__device__ __forceinline__ float bf2f(unsigned short h) {
  union { unsigned u; float f; } v; v.u = ((unsigned)h) << 16;
  return v.f;
}
__device__ __forceinline__ float gelu_exact(float g) {
  return 0.5f * g * (1.0f + erff(g * 0.70710678118654752f));
}

// ---------------- gating: one wave per token ----------------
__global__ __launch_bounds__(64) void k_gate(const float* __restrict__ x,
    const float* __restrict__ gw, int* __restrict__ topk_idx,
    float* __restrict__ topk_w, int* __restrict__ cnt)
{
  const int t = blockIdx.x;
  const int lane = threadIdx.x;
  const float* xr = x + (size_t)t * 1024;
  float xv[16];
#pragma unroll
  for (int i = 0; i < 16; i++) xv[i] = xr[lane + 64 * i];
  float p[15];
  float m = -1e30f;
#pragma unroll
  for (int e = 0; e < 15; e++) {
    const float* wr = gw + (size_t)e * 1024;
    float s = 0.f;
#pragma unroll
    for (int i = 0; i < 16; i++) s += xv[i] * wr[lane + 64 * i];
#pragma unroll
    for (int o = 32; o; o >>= 1) s += __shfl_xor(s, o, 64);
    p[e] = s;
    m = fmaxf(m, s);
  }
  float Z = 0.f;
#pragma unroll
  for (int e = 0; e < 15; e++) { p[e] = expf(p[e] - m); Z += p[e]; }
  int usedMask = 0;
  int bi[3]; float bv[3];
#pragma unroll
  for (int j = 0; j < 3; j++) {
    float best = -1.f; int b = 0;
#pragma unroll
    for (int e = 0; e < 15; e++) {
      bool ok = (!((usedMask >> e) & 1)) && (p[e] > best);
      if (ok) { best = p[e]; b = e; }
    }
    bi[j] = b; bv[j] = best / Z;
    usedMask |= 1 << b;
  }
  if (lane == 0) {
    float den = bv[0] + bv[1] + bv[2] + 1e-20f;
#pragma unroll
    for (int j = 0; j < 3; j++) {
      topk_idx[t * 3 + j] = bi[j];
      topk_w[t * 3 + j] = bv[j] / den;
      atomicAdd(&cnt[bi[j]], 1);
    }
  }
}

__global__ void k_prefix(const int* __restrict__ cnt, int* __restrict__ offs) {
  if (threadIdx.x == 0) {
    int a = 0;
    for (int e = 0; e < 15; e++) { offs[e] = a; a += cnt[e]; }
  }
}

__global__ __launch_bounds__(256) void k_assign(const int* __restrict__ topk_idx,
    const float* __restrict__ topk_w, const int* __restrict__ offs,
    int* __restrict__ fill, int* __restrict__ row_tok, float* __restrict__ row_wt,
    int* __restrict__ row_id)
{
  int t = blockIdx.x * 256 + threadIdx.x;
  if (t >= 2048) return;
  for (int j = 0; j < 3; j++) {
    int e = topk_idx[t * 3 + j];
    int pos = atomicAdd(&fill[e], 1);
    int row = offs[e] + pos;
    row_tok[row] = t;
    row_wt[row] = topk_w[t * 3 + j];
    row_id[t * 3 + j] = row;
  }
}

// ---------------- shared expert fc1 + geglu -> as_buf (bf16, 2048x2048) ----------------
__global__ __launch_bounds__(256) void k_shared_fc1(const float* __restrict__ x,
    const float* __restrict__ w, const float* __restrict__ b,
    const float* __restrict__ mult, short* __restrict__ as_buf)
{
  __shared__ short As[64 * SA], Bs1[64 * SA], Bs2[64 * SA];
  const int tid = threadIdx.x;
  const int m0 = blockIdx.y * 64;
  const int f0 = blockIdx.x * 64;
  const int lane = tid & 63, wid = tid >> 6;
  const int wr = wid >> 1, wc = wid & 1;
  const int lr = tid >> 4, kq = tid & 15;
  f32x4 acc1[2][2] = {}, acc2[2][2] = {};
  for (int k0 = 0; k0 < 1024; k0 += 64) {
#pragma unroll
    for (int rr = 0; rr < 4; rr++) {
      int r = lr + rr * 16;
      const float4 av  = *(const float4*)(x + (size_t)(m0 + r) * 1024 + k0 + kq * 4);
      const float4 bv1 = *(const float4*)(w + (size_t)(f0 + r) * 1024 + k0 + kq * 4);
      const float4 bv2 = *(const float4*)(w + (size_t)(2048 + f0 + r) * 1024 + k0 + kq * 4);
      *(short4*)&As[r * SA + kq * 4]  = make_short4(f2bf(av.x),  f2bf(av.y),  f2bf(av.z),  f2bf(av.w));
      *(short4*)&Bs1[r * SA + kq * 4] = make_short4(f2bf(bv1.x), f2bf(bv1.y), f2bf(bv1.z), f2bf(bv1.w));
      *(short4*)&Bs2[r * SA + kq * 4] = make_short4(f2bf(bv2.x), f2bf(bv2.y), f2bf(bv2.z), f2bf(bv2.w));
    }
    __syncthreads();
#pragma unroll
    for (int kk = 0; kk < 64; kk += 32) {
      const int kf = kk + (lane >> 4) * 8;
      const int ml = lane & 15;
      bfrag a0 = *(bfrag*)&As[(wr * 32 + ml) * SA + kf];
      bfrag a1 = *(bfrag*)&As[(wr * 32 + 16 + ml) * SA + kf];
      bfrag p0 = *(bfrag*)&Bs1[(wc * 32 + ml) * SA + kf];
      bfrag p1 = *(bfrag*)&Bs1[(wc * 32 + 16 + ml) * SA + kf];
      bfrag q0 = *(bfrag*)&Bs2[(wc * 32 + ml) * SA + kf];
      bfrag q1 = *(bfrag*)&Bs2[(wc * 32 + 16 + ml) * SA + kf];
      acc1[0][0] = __builtin_amdgcn_mfma_f32_16x16x32_bf16(a0, p0, acc1[0][0], 0, 0, 0);
      acc1[0][1] = __builtin_amdgcn_mfma_f32_16x16x32_bf16(a0, p1, acc1[0][1], 0, 0, 0);
      acc1[1][0] = __builtin_amdgcn_mfma_f32_16x16x32_bf16(a1, p0, acc1[1][0], 0, 0, 0);
      acc1[1][1] = __builtin_amdgcn_mfma_f32_16x16x32_bf16(a1, p1, acc1[1][1], 0, 0, 0);
      acc2[0][0] = __builtin_amdgcn_mfma_f32_16x16x32_bf16(a0, q0, acc2[0][0], 0, 0, 0);
      acc2[0][1] = __builtin_amdgcn_mfma_f32_16x16x32_bf16(a0, q1, acc2[0][1], 0, 0, 0);
      acc2[1][0] = __builtin_amdgcn_mfma_f32_16x16x32_bf16(a1, q0, acc2[1][0], 0, 0, 0);
      acc2[1][1] = __builtin_amdgcn_mfma_f32_16x16x32_bf16(a1, q1, acc2[1][1], 0, 0, 0);
    }
    __syncthreads();
  }
  const int colL = lane & 15, rowq = lane >> 4;
#pragma unroll
  for (int j = 0; j < 2; j++) {
    const int f = f0 + wc * 32 + j * 16 + colL;
    const float b1v = b[f], b2v = b[2048 + f], mv = mult[f];
#pragma unroll
    for (int i = 0; i < 2; i++) {
#pragma unroll
      for (int rg = 0; rg < 4; rg++) {
        const int m = m0 + wr * 32 + i * 16 + rowq * 4 + rg;
        const float h1 = acc1[i][j][rg] + b1v;
        const float h2 = acc2[i][j][rg] + b2v;
        as_buf[(size_t)m * 2048 + f] = f2bf(gelu_exact(h2) * h1 * mv);
      }
    }
  }
}

// ---------------- shared expert fc2 -> y (plain f32 store, covers all) ----------------
__global__ __launch_bounds__(256) void k_shared_fc2(const short* __restrict__ as_buf,
    const float* __restrict__ w, const float* __restrict__ b, float* __restrict__ y)
{
  __shared__ short As[64 * SA], Bs[64 * SA];
  const int tid = threadIdx.x;
  const int m0 = blockIdx.y * 64;
  const int d0 = blockIdx.x * 64;
  const int lane = tid & 63, wid = tid >> 6;
  const int wr = wid >> 1, wc = wid & 1;
  const int lr8 = tid >> 3, c8 = tid & 7;
  const int lr = tid >> 4, kq = tid & 15;
  f32x4 acc[2][2] = {};
  for (int k0 = 0; k0 < 2048; k0 += 64) {
#pragma unroll
    for (int rr = 0; rr < 2; rr++) {
      int r = lr8 + rr * 32;
      *(int4*)&As[r * SA + c8 * 8] = *(const int4*)(as_buf + (size_t)(m0 + r) * 2048 + k0 + c8 * 8);
    }
#pragma unroll
    for (int rr = 0; rr < 4; rr++) {
      int r = lr + rr * 16;
      const float4 bv = *(const float4*)(w + (size_t)(d0 + r) * 2048 + k0 + kq * 4);
      *(short4*)&Bs[r * SA + kq * 4] = make_short4(f2bf(bv.x), f2bf(bv.y), f2bf(bv.z), f2bf(bv.w));
    }
    __syncthreads();
#pragma unroll
    for (int kk = 0; kk < 64; kk += 32) {
      const int kf = kk + (lane >> 4) * 8;
      const int ml = lane & 15;
      bfrag a0 = *(bfrag*)&As[(wr * 32 + ml) * SA + kf];
      bfrag a1 = *(bfrag*)&As[(wr * 32 + 16 + ml) * SA + kf];
      bfrag b0 = *(bfrag*)&Bs[(wc * 32 + ml) * SA + kf];
      bfrag b1 = *(bfrag*)&Bs[(wc * 32 + 16 + ml) * SA + kf];
      acc[0][0] = __builtin_amdgcn_mfma_f32_16x16x32_bf16(a0, b0, acc[0][0], 0, 0, 0);
      acc[0][1] = __builtin_amdgcn_mfma_f32_16x16x32_bf16(a0, b1, acc[0][1], 0, 0, 0);
      acc[1][0] = __builtin_amdgcn_mfma_f32_16x16x32_bf16(a1, b0, acc[1][0], 0, 0, 0);
      acc[1][1] = __builtin_amdgcn_mfma_f32_16x16x32_bf16(a1, b1, acc[1][1], 0, 0, 0);
    }
    __syncthreads();
  }
  const int colL = lane & 15, rowq = lane >> 4;
#pragma unroll
  for (int j = 0; j < 2; j++) {
    const int d = d0 + wc * 32 + j * 16 + colL;
    const float bvv = b[d];
#pragma unroll
    for (int i = 0; i < 2; i++) {
#pragma unroll
      for (int rg = 0; rg < 4; rg++) {
        const int m = m0 + wr * 32 + i * 16 + rowq * 4 + rg;
        y[(size_t)m * 1024 + d] = acc[i][j][rg] + bvv;
      }
    }
  }
}

// ---------------- expert tile resolver ----------------
__device__ __forceinline__ bool resolve_tile(const int* __restrict__ cnt, int ty,
                                             int& e, int& lt) {
  int acc = 0;
#pragma unroll
  for (int i = 0; i < 15; i++) {
    int tiles = (cnt[i] + 63) >> 6;
    if (ty < acc + tiles) { e = i; lt = ty - acc; return true; }
    acc += tiles;
  }
  return false;
}

// ---------------- expert fc1 + geglu -> a_buf (bf16, compacted rows x 1024) ----------------
__global__ __launch_bounds__(256) void k_exp_fc1(const float* __restrict__ x,
    const float* __restrict__ fc1_w, const float* __restrict__ fc1_b,
    const float* __restrict__ gmult, const int* __restrict__ cnt,
    const int* __restrict__ offs, const int* __restrict__ row_tok,
    short* __restrict__ a_buf)
{
  int e, lt;
  if (!resolve_tile(cnt, blockIdx.y, e, lt)) return;
  __shared__ short As[64 * SA], Bs1[64 * SA], Bs2[64 * SA];
  const int tid = threadIdx.x;
  const int f0 = blockIdx.x * 64;
  const int rowBase = offs[e] + lt * 64;
  int nrows = cnt[e] - lt * 64; if (nrows > 64) nrows = 64;
  const int lane = tid & 63, wid = tid >> 6;
  const int wr = wid >> 1, wc = wid & 1;
  const int lr = tid >> 4, kq = tid & 15;
  int tok[4];
#pragma unroll
  for (int rr = 0; rr < 4; rr++) {
    int r = lr + rr * 16;
    tok[rr] = row_tok[rowBase + (r < nrows ? r : 0)];
  }
  const float* wbase = fc1_w + (size_t)e * 2048 * 1024;
  f32x4 acc1[2][2] = {}, acc2[2][2] = {};
  for (int k0 = 0; k0 < 1024; k0 += 64) {
#pragma unroll
    for (int rr = 0; rr < 4; rr++) {
      int r = lr + rr * 16;
      const float4 av  = *(const float4*)(x + (size_t)tok[rr] * 1024 + k0 + kq * 4);
      const float4 bv1 = *(const float4*)(wbase + (size_t)(f0 + r) * 1024 + k0 + kq * 4);
      const float4 bv2 = *(const float4*)(wbase + (size_t)(1024 + f0 + r) * 1024 + k0 + kq * 4);
      *(short4*)&As[r * SA + kq * 4]  = make_short4(f2bf(av.x),  f2bf(av.y),  f2bf(av.z),  f2bf(av.w));
      *(short4*)&Bs1[r * SA + kq * 4] = make_short4(f2bf(bv1.x), f2bf(bv1.y), f2bf(bv1.z), f2bf(bv1.w));
      *(short4*)&Bs2[r * SA + kq * 4] = make_short4(f2bf(bv2.x), f2bf(bv2.y), f2bf(bv2.z), f2bf(bv2.w));
    }
    __syncthreads();
#pragma unroll
    for (int kk = 0; kk < 64; kk += 32) {
      const int kf = kk + (lane >> 4) * 8;
      const int ml = lane & 15;
      bfrag a0 = *(bfrag*)&As[(wr * 32 + ml) * SA + kf];
      bfrag a1 = *(bfrag*)&As[(wr * 32 + 16 + ml) * SA + kf];
      bfrag p0 = *(bfrag*)&Bs1[(wc * 32 + ml) * SA + kf];
      bfrag p1 = *(bfrag*)&Bs1[(wc * 32 + 16 + ml) * SA + kf];
      bfrag q0 = *(bfrag*)&Bs2[(wc * 32 + ml) * SA + kf];
      bfrag q1 = *(bfrag*)&Bs2[(wc * 32 + 16 + ml) * SA + kf];
      acc1[0][0] = __builtin_amdgcn_mfma_f32_16x16x32_bf16(a0, p0, acc1[0][0], 0, 0, 0);
      acc1[0][1] = __builtin_amdgcn_mfma_f32_16x16x32_bf16(a0, p1, acc1[0][1], 0, 0, 0);
      acc1[1][0] = __builtin_amdgcn_mfma_f32_16x16x32_bf16(a1, p0, acc1[1][0], 0, 0, 0);
      acc1[1][1] = __builtin_amdgcn_mfma_f32_16x16x32_bf16(a1, p1, acc1[1][1], 0, 0, 0);
      acc2[0][0] = __builtin_amdgcn_mfma_f32_16x16x32_bf16(a0, q0, acc2[0][0], 0, 0, 0);
      acc2[0][1] = __builtin_amdgcn_mfma_f32_16x16x32_bf16(a0, q1, acc2[0][1], 0, 0, 0);
      acc2[1][0] = __builtin_amdgcn_mfma_f32_16x16x32_bf16(a1, q0, acc2[1][0], 0, 0, 0);
      acc2[1][1] = __builtin_amdgcn_mfma_f32_16x16x32_bf16(a1, q1, acc2[1][1], 0, 0, 0);
    }
    __syncthreads();
  }
  const int colL = lane & 15, rowq = lane >> 4;
#pragma unroll
  for (int j = 0; j < 2; j++) {
    const int f = f0 + wc * 32 + j * 16 + colL;
    const float b1v = fc1_b[(size_t)e * 2048 + f];
    const float b2v = fc1_b[(size_t)e * 2048 + 1024 + f];
    const float mv = gmult[(size_t)e * 1024 + f];
#pragma unroll
    for (int i = 0; i < 2; i++) {
#pragma unroll
      for (int rg = 0; rg < 4; rg++) {
        const int mrow = wr * 32 + i * 16 + rowq * 4 + rg;
        if (mrow < nrows) {
          const float h1 = acc1[i][j][rg] + b1v;
          const float h2 = acc2[i][j][rg] + b2v;
          a_buf[(size_t)(rowBase + mrow) * 1024 + f] = f2bf(gelu_exact(h2) * h1 * mv);
        }
      }
    }
  }
}

// ---------------- expert fc2 -> yexp_buf (bf16, bias + weight applied) ----------------
__global__ __launch_bounds__(256) void k_exp_fc2(const short* __restrict__ a_buf,
    const float* __restrict__ fc2_w, const float* __restrict__ fc2_b,
    const int* __restrict__ cnt, const int* __restrict__ offs,
    const float* __restrict__ row_wt, short* __restrict__ yexp)
{
  int e, lt;
  if (!resolve_tile(cnt, blockIdx.y, e, lt)) return;
  __shared__ short As[64 * SA], Bs[64 * SA];
  const int tid = threadIdx.x;
  const int d0 = blockIdx.x * 64;
  const int rowBase = offs[e] + lt * 64;
  int nrows = cnt[e] - lt * 64; if (nrows > 64) nrows = 64;
  const int lane = tid & 63, wid = tid >> 6;
  const int wr = wid >> 1, wc = wid & 1;
  const int lr8 = tid >> 3, c8 = tid & 7;
  const int lr = tid >> 4, kq = tid & 15;
  const float* wbase = fc2_w + (size_t)e * 1024 * 1024;
  f32x4 acc[2][2] = {};
  for (int k0 = 0; k0 < 1024; k0 += 64) {
#pragma unroll
    for (int rr = 0; rr < 2; rr++) {
      int r = lr8 + rr * 32;
      *(int4*)&As[r * SA + c8 * 8] = *(const int4*)(a_buf + (size_t)(rowBase + r) * 1024 + k0 + c8 * 8);
    }
#pragma unroll
    for (int rr = 0; rr < 4; rr++) {
      int r = lr + rr * 16;
      const float4 bv = *(const float4*)(wbase + (size_t)(d0 + r) * 1024 + k0 + kq * 4);
      *(short4*)&Bs[r * SA + kq * 4] = make_short4(f2bf(bv.x), f2bf(bv.y), f2bf(bv.z), f2bf(bv.w));
    }
    __syncthreads();
#pragma unroll
    for (int kk = 0; kk < 64; kk += 32) {
      const int kf = kk + (lane >> 4) * 8;
      const int ml = lane & 15;
      bfrag a0 = *(bfrag*)&As[(wr * 32 + ml) * SA + kf];
      bfrag a1 = *(bfrag*)&As[(wr * 32 + 16 + ml) * SA + kf];
      bfrag b0 = *(bfrag*)&Bs[(wc * 32 + ml) * SA + kf];
      bfrag b1 = *(bfrag*)&Bs[(wc * 32 + 16 + ml) * SA + kf];
      acc[0][0] = __builtin_amdgcn_mfma_f32_16x16x32_bf16(a0, b0, acc[0][0], 0, 0, 0);
      acc[0][1] = __builtin_amdgcn_mfma_f32_16x16x32_bf16(a0, b1, acc[0][1], 0, 0, 0);
      acc[1][0] = __builtin_amdgcn_mfma_f32_16x16x32_bf16(a1, b0, acc[1][0], 0, 0, 0);
      acc[1][1] = __builtin_amdgcn_mfma_f32_16x16x32_bf16(a1, b1, acc[1][1], 0, 0, 0);
    }
    __syncthreads();
  }
  const int colL = lane & 15, rowq = lane >> 4;
#pragma unroll
  for (int j = 0; j < 2; j++) {
    const int d = d0 + wc * 32 + j * 16 + colL;
    const float bvv = fc2_b[(size_t)e * 1024 + d];
#pragma unroll
    for (int i = 0; i < 2; i++) {
#pragma unroll
      for (int rg = 0; rg < 4; rg++) {
        const int mrow = wr * 32 + i * 16 + rowq * 4 + rg;
        if (mrow < nrows) {
          const float wt = row_wt[rowBase + mrow];
          yexp[(size_t)(rowBase + mrow) * 1024 + d] = f2bf((acc[i][j][rg] + bvv) * wt);
        }
      }
    }
  }
}

// ---------------- combine: y += sum of 3 gathered expert rows ----------------
__global__ __launch_bounds__(256) void k_combine(float* __restrict__ y,
    const short* __restrict__ yexp, const int* __restrict__ row_id)
{
  const int idx = blockIdx.x * 256 + threadIdx.x;
  const int t = idx >> 8;
  const int d4 = (idx & 255) * 4;
  const int r0 = row_id[t * 3], r1 = row_id[t * 3 + 1], r2 = row_id[t * 3 + 2];
  float4 acc = *(float4*)(y + (size_t)t * 1024 + d4);
  const ushort4 v0 = *(const ushort4*)(yexp + (size_t)r0 * 1024 + d4);
  const ushort4 v1 = *(const ushort4*)(yexp + (size_t)r1 * 1024 + d4);
  const ushort4 v2 = *(const ushort4*)(yexp + (size_t)r2 * 1024 + d4);
  acc.x += bf2f(v0.x) + bf2f(v1.x) + bf2f(v2.x);
  acc.y += bf2f(v0.y) + bf2f(v1.y) + bf2f(v2.y);
  acc.z += bf2f(v0.z) + bf2f(v1.z) + bf2f(v2.z);
  acc.w += bf2f(v0.w) + bf2f(v1.w) + bf2f(v2.w);
  *(float4*)(y + (size_t)t * 1024 + d4) = acc;
}

extern "C" void kernel_launch(void* const* d_in, const int* in_sizes, int n_in,
                              void* d_out, int out_size, void* d_ws, size_t ws_size,
                              hipStream_t stream) {
  const float* x          = (const float*)d_in[0];
  const float* gate_w     = (const float*)d_in[1];
  const float* fc1_w      = (const float*)d_in[2];
  const float* fc1_b      = (const float*)d_in[3];
  const float* geglu_mult = (const float*)d_in[4];
  const float* fc2_w      = (const float*)d_in[5];
  const float* fc2_b      = (const float*)d_in[6];
  const float* s_fc1_w    = (const float*)d_in[7];
  const float* s_fc1_b    = (const float*)d_in[8];
  const float* s_mult     = (const float*)d_in[9];
  const float* s_fc2_w    = (const float*)d_in[10];
  const float* s_fc2_b    = (const float*)d_in[11];
  float* y = (float*)d_out;

  char* wsb = (char*)d_ws;
  int*   cnt      = (int*)(wsb + 0);                      // 16 ints
  int*   fill     = (int*)(wsb + 64);                     // 16 ints
  int*   offs     = (int*)(wsb + 128);                    // 16 ints
  int*   topk_idx = (int*)(wsb + 256);                    // 6144
  float* topk_w   = (float*)(wsb + 256 + 24576);          // 6144
  int*   row_tok  = (int*)(wsb + 256 + 2 * 24576);        // 6272
  float* row_wt   = (float*)(wsb + 256 + 2 * 24576 + 25088);       // 6272
  int*   row_id   = (int*)(wsb + 256 + 2 * 24576 + 2 * 25088);     // 6144
  short* a_buf    = (short*)(wsb + 131072);                         // 6208x1024 bf16
  short* yexp_buf = (short*)(wsb + 131072 + 12713984);              // 6208x1024 bf16
  short* as_buf   = (short*)(wsb + 131072 + 2 * 12713984);          // 2048x2048 bf16
  // total ws use ~32.4 MB

  hipMemsetAsync(d_ws, 0, 256, stream);  // zero cnt/fill/offs
  k_gate<<<2048, 64, 0, stream>>>(x, gate_w, topk_idx, topk_w, cnt);
  k_prefix<<<1, 64, 0, stream>>>(cnt, offs);
  k_assign<<<8, 256, 0, stream>>>(topk_idx, topk_w, offs, fill, row_tok, row_wt, row_id);
  k_shared_fc1<<<dim3(32, 32), 256, 0, stream>>>(x, s_fc1_w, s_fc1_b, s_mult, as_buf);
  k_shared_fc2<<<dim3(16, 32), 256, 0, stream>>>(as_buf, s_fc2_w, s_fc2_b, y);
  k_exp_fc1<<<dim3(16, 111), 256, 0, stream>>>(x, fc1_w, fc1_b, geglu_mult, cnt, offs, row_tok, a_buf);
  k_exp_fc2<<<dim3(16, 111), 256, 0, stream>>>(a_buf, fc2_w, fc2_b, cnt, offs, row_wt, yexp_buf);
  k_combine<<<2048, 256, 0, stream>>>(y, yexp_buf, row_id);
}

// Round 2
// 599.038 us; speedup vs baseline: 1.2004x; 1.2004x over previous
//
#include <hip/hip_runtime.h>

typedef __attribute__((ext_vector_type(8))) short bfrag;
typedef __attribute__((ext_vector_type(4))) float f32x4;

#define LDA 72  // LDS row stride in bf16 (64 + 8 pad -> 2-way bank alias only, free)

__device__ __forceinline__ short f2bf(float f) {
  union { float f; unsigned u; } v; v.f = f;
  unsigned r = v.u + 0x7FFFu + ((v.u >> 16) & 1u);  // RNE
  return (short)(r >> 16);
}
__device__ __forceinline__ float bf2f(unsigned short h) {
  union { unsigned u; float f; } v; v.u = ((unsigned)h) << 16;
  return v.f;
}
__device__ __forceinline__ float gelu_exact(float g) {
  return 0.5f * g * (1.0f + erff(g * 0.70710678118654752f));
}

union Pack8 { short s[8]; int4 v; };

// ---------------- x -> bf16 ----------------
__global__ __launch_bounds__(256) void k_convert_x(const float* __restrict__ x,
                                                   short* __restrict__ xbf) {
  const int idx = blockIdx.x * 256 + threadIdx.x;  // 524288 float4s
  const float4 v = ((const float4*)x)[idx];
  ((short4*)xbf)[idx] = make_short4(f2bf(v.x), f2bf(v.y), f2bf(v.z), f2bf(v.w));
}

// ---------------- gating: one wave per 4 tokens, NO global atomics ----------------
__global__ __launch_bounds__(64) void k_gate(const float* __restrict__ x,
    const float* __restrict__ gw, int* __restrict__ topk_idx,
    float* __restrict__ topk_w)
{
  const int t0 = blockIdx.x * 4;
  const int lane = threadIdx.x;
  float xv[4][16];
#pragma unroll
  for (int tt = 0; tt < 4; tt++)
#pragma unroll
    for (int i = 0; i < 16; i++) xv[tt][i] = x[(size_t)(t0 + tt) * 1024 + lane + 64 * i];
  float p[4][15];
#pragma unroll
  for (int e = 0; e < 15; e++) {
    float wv[16];
#pragma unroll
    for (int i = 0; i < 16; i++) wv[i] = gw[(size_t)e * 1024 + lane + 64 * i];
#pragma unroll
    for (int tt = 0; tt < 4; tt++) {
      float s = 0.f;
#pragma unroll
      for (int i = 0; i < 16; i++) s += xv[tt][i] * wv[i];
#pragma unroll
      for (int o = 32; o; o >>= 1) s += __shfl_xor(s, o, 64);
      p[tt][e] = s;  // all lanes hold full sum
    }
  }
#pragma unroll
  for (int tt = 0; tt < 4; tt++) {
    float m = -1e30f;
#pragma unroll
    for (int e = 0; e < 15; e++) m = fmaxf(m, p[tt][e]);
    float q[15], Z = 0.f;
#pragma unroll
    for (int e = 0; e < 15; e++) { q[e] = expf(p[tt][e] - m); Z += q[e]; }
    int usedMask = 0; int bi[3]; float bv[3];
#pragma unroll
    for (int j = 0; j < 3; j++) {
      float best = -1.f; int b = 0;
#pragma unroll
      for (int e = 0; e < 15; e++) {
        bool ok = (!((usedMask >> e) & 1)) && (q[e] > best);
        if (ok) { best = q[e]; b = e; }
      }
      bi[j] = b; bv[j] = best / Z; usedMask |= 1 << b;
    }
    if (lane == tt) {
      float den = bv[0] + bv[1] + bv[2] + 1e-20f;
#pragma unroll
      for (int j = 0; j < 3; j++) {
        topk_idx[(t0 + tt) * 3 + j] = bi[j];
        topk_w[(t0 + tt) * 3 + j] = bv[j] / den;
      }
    }
  }
}

// ---------------- routing: single block, LDS atomics only ----------------
__global__ __launch_bounds__(1024) void k_route(const int* __restrict__ topk_idx,
    const float* __restrict__ topk_w, int* __restrict__ cnt_g, int* __restrict__ offs_g,
    int* __restrict__ row_tok, float* __restrict__ row_wt, int* __restrict__ row_id)
{
  __shared__ int scnt[16], soffs[16], sfill[16];
  const int tid = threadIdx.x;
  if (tid < 16) { scnt[tid] = 0; sfill[tid] = 0; }
  __syncthreads();
  for (int i = tid; i < 6144; i += 1024) atomicAdd(&scnt[topk_idx[i]], 1);
  __syncthreads();
  if (tid == 0) {
    int a = 0;
    for (int e = 0; e < 15; e++) { soffs[e] = a; offs_g[e] = a; cnt_g[e] = scnt[e]; a += scnt[e]; }
  }
  __syncthreads();
  for (int i = tid; i < 6144; i += 1024) {
    int e = topk_idx[i];
    int pos = atomicAdd(&sfill[e], 1);
    int row = soffs[e] + pos;
    row_tok[row] = i / 3;
    row_wt[row] = topk_w[i];
    row_id[i] = row;
  }
}

__device__ __forceinline__ bool resolve_tile128(const int* __restrict__ cnt, int ty,
                                                int& e, int& lt) {
  int acc = 0;
#pragma unroll
  for (int i = 0; i < 15; i++) {
    int tl = (cnt[i] + 127) >> 7;
    if (ty < acc + tl) { e = i; lt = ty - acc; return true; }
    acc += tl;
  }
  return false;
}

// ================= 128x128 GEMM kernels, BK=64, 4 waves in 2x2 =================
// common: tid 0..255; lane=tid&63; ml=lane&15; kq=lane>>4; wr=(tid>>6)>>1; wc=(tid>>6)&1
// stage: thread owns column-chunk c=tid&7 (8 elems), rows r0+32i (r0=tid>>3, i=0..3)

// ---------------- expert fc1 + geglu (dual-half B: rows 0-63 = h1, 64-127 = h2) ----------------
__global__ __launch_bounds__(256) void k_exp_fc1(const short* __restrict__ xbf,
    const float* __restrict__ fc1_w, const float* __restrict__ fc1_b,
    const float* __restrict__ gmult, const int* __restrict__ cnt,
    const int* __restrict__ offs, const int* __restrict__ row_tok,
    short* __restrict__ a_buf)
{
  int e, lt;
  if (!resolve_tile128(cnt, blockIdx.y, e, lt)) return;
  __shared__ short smem[2 * 128 * LDA];
  short* As = smem;
  short* Bs = smem + 128 * LDA;
  const int tid = threadIdx.x;
  const int f0 = blockIdx.x * 64;
  const int rowBase = offs[e] + lt * 128;
  int nrows = cnt[e] - lt * 128; if (nrows > 128) nrows = 128;
  const int lane = tid & 63, ml = lane & 15, kq = lane >> 4;
  const int wr = (tid >> 6) >> 1, wc = (tid >> 6) & 1;
  const int r0 = tid >> 3, c = tid & 7;
  const float* wbase = fc1_w + (size_t)e * 2048 * 1024;
  const short* aP[4]; const float* bP[4];
#pragma unroll
  for (int i = 0; i < 4; i++) {
    int r = r0 + 32 * i;
    int rc = r < nrows ? r : nrows - 1;
    aP[i] = xbf + (size_t)row_tok[rowBase + rc] * 1024 + c * 8;
    int grow = (r < 64) ? (f0 + r) : (1024 + f0 + r - 64);
    bP[i] = wbase + (size_t)grow * 1024 + c * 8;
  }
  f32x4 acc[4][4] = {};
  for (int k0 = 0; k0 < 1024; k0 += 64) {
#pragma unroll
    for (int i = 0; i < 4; i++) {
      int r = r0 + 32 * i;
      *(int4*)&As[r * LDA + c * 8] = *(const int4*)(aP[i] + k0);
      float4 lo = *(const float4*)(bP[i] + k0);
      float4 hi = *(const float4*)(bP[i] + k0 + 4);
      Pack8 pk;
      pk.s[0] = f2bf(lo.x); pk.s[1] = f2bf(lo.y); pk.s[2] = f2bf(lo.z); pk.s[3] = f2bf(lo.w);
      pk.s[4] = f2bf(hi.x); pk.s[5] = f2bf(hi.y); pk.s[6] = f2bf(hi.z); pk.s[7] = f2bf(hi.w);
      *(int4*)&Bs[r * LDA + c * 8] = pk.v;
    }
    __syncthreads();
#pragma unroll
    for (int kk = 0; kk < 2; kk++) {
      const int kbase = kk * 32 + kq * 8;
      bfrag a[4], b[4];
#pragma unroll
      for (int i = 0; i < 4; i++) a[i] = *(bfrag*)&As[(wr * 64 + i * 16 + ml) * LDA + kbase];
#pragma unroll
      for (int j = 0; j < 4; j++) b[j] = *(bfrag*)&Bs[(wc * 64 + j * 16 + ml) * LDA + kbase];
#pragma unroll
      for (int i = 0; i < 4; i++)
#pragma unroll
        for (int j = 0; j < 4; j++)
          acc[i][j] = __builtin_amdgcn_mfma_f32_16x16x32_bf16(a[i], b[j], acc[i][j], 0, 0, 0);
    }
    __syncthreads();
  }
  // geglu epilogue: wc==1 holds h2 (cols f0..f0+63), wc==0 holds h1
  float* hbuf = (float*)smem;  // 128x64 f32 = 32KB <= 36KB
  if (wc == 1) {
#pragma unroll
    for (int j = 0; j < 4; j++) {
      const int fl = j * 16 + ml;
      const float b2 = fc1_b[(size_t)e * 2048 + 1024 + f0 + fl];
#pragma unroll
      for (int i = 0; i < 4; i++)
#pragma unroll
        for (int rg = 0; rg < 4; rg++) {
          const int row = wr * 64 + i * 16 + kq * 4 + rg;
          hbuf[row * 64 + fl] = acc[i][j][rg] + b2;
        }
    }
  }
  __syncthreads();
  if (wc == 0) {
#pragma unroll
    for (int j = 0; j < 4; j++) {
      const int fl = j * 16 + ml;
      const float b1 = fc1_b[(size_t)e * 2048 + f0 + fl];
      const float mv = gmult[(size_t)e * 1024 + f0 + fl];
#pragma unroll
      for (int i = 0; i < 4; i++)
#pragma unroll
        for (int rg = 0; rg < 4; rg++) {
          const int row = wr * 64 + i * 16 + kq * 4 + rg;
          if (row < nrows) {
            const float h1 = acc[i][j][rg] + b1;
            const float h2 = hbuf[row * 64 + fl];
            a_buf[(size_t)(rowBase + row) * 1024 + f0 + fl] = f2bf(gelu_exact(h2) * h1 * mv);
          }
        }
    }
  }
}

// ---------------- shared fc1 + geglu ----------------
__global__ __launch_bounds__(256) void k_shared_fc1(const short* __restrict__ xbf,
    const float* __restrict__ w, const float* __restrict__ b,
    const float* __restrict__ mult, short* __restrict__ as_buf)
{
  __shared__ short smem[2 * 128 * LDA];
  short* As = smem;
  short* Bs = smem + 128 * LDA;
  const int tid = threadIdx.x;
  const int f0 = blockIdx.x * 64;
  const int m0 = blockIdx.y * 128;
  const int lane = tid & 63, ml = lane & 15, kq = lane >> 4;
  const int wr = (tid >> 6) >> 1, wc = (tid >> 6) & 1;
  const int r0 = tid >> 3, c = tid & 7;
  const short* aP[4]; const float* bP[4];
#pragma unroll
  for (int i = 0; i < 4; i++) {
    int r = r0 + 32 * i;
    aP[i] = xbf + (size_t)(m0 + r) * 1024 + c * 8;
    int grow = (r < 64) ? (f0 + r) : (2048 + f0 + r - 64);
    bP[i] = w + (size_t)grow * 1024 + c * 8;
  }
  f32x4 acc[4][4] = {};
  for (int k0 = 0; k0 < 1024; k0 += 64) {
#pragma unroll
    for (int i = 0; i < 4; i++) {
      int r = r0 + 32 * i;
      *(int4*)&As[r * LDA + c * 8] = *(const int4*)(aP[i] + k0);
      float4 lo = *(const float4*)(bP[i] + k0);
      float4 hi = *(const float4*)(bP[i] + k0 + 4);
      Pack8 pk;
      pk.s[0] = f2bf(lo.x); pk.s[1] = f2bf(lo.y); pk.s[2] = f2bf(lo.z); pk.s[3] = f2bf(lo.w);
      pk.s[4] = f2bf(hi.x); pk.s[5] = f2bf(hi.y); pk.s[6] = f2bf(hi.z); pk.s[7] = f2bf(hi.w);
      *(int4*)&Bs[r * LDA + c * 8] = pk.v;
    }
    __syncthreads();
#pragma unroll
    for (int kk = 0; kk < 2; kk++) {
      const int kbase = kk * 32 + kq * 8;
      bfrag a[4], bb[4];
#pragma unroll
      for (int i = 0; i < 4; i++) a[i] = *(bfrag*)&As[(wr * 64 + i * 16 + ml) * LDA + kbase];
#pragma unroll
      for (int j = 0; j < 4; j++) bb[j] = *(bfrag*)&Bs[(wc * 64 + j * 16 + ml) * LDA + kbase];
#pragma unroll
      for (int i = 0; i < 4; i++)
#pragma unroll
        for (int j = 0; j < 4; j++)
          acc[i][j] = __builtin_amdgcn_mfma_f32_16x16x32_bf16(a[i], bb[j], acc[i][j], 0, 0, 0);
    }
    __syncthreads();
  }
  float* hbuf = (float*)smem;
  if (wc == 1) {
#pragma unroll
    for (int j = 0; j < 4; j++) {
      const int fl = j * 16 + ml;
      const float b2 = b[2048 + f0 + fl];
#pragma unroll
      for (int i = 0; i < 4; i++)
#pragma unroll
        for (int rg = 0; rg < 4; rg++) {
          const int row = wr * 64 + i * 16 + kq * 4 + rg;
          hbuf[row * 64 + fl] = acc[i][j][rg] + b2;
        }
    }
  }
  __syncthreads();
  if (wc == 0) {
#pragma unroll
    for (int j = 0; j < 4; j++) {
      const int fl = j * 16 + ml;
      const float b1 = b[f0 + fl];
      const float mv = mult[f0 + fl];
#pragma unroll
      for (int i = 0; i < 4; i++)
#pragma unroll
        for (int rg = 0; rg < 4; rg++) {
          const int row = wr * 64 + i * 16 + kq * 4 + rg;
          const float h1 = acc[i][j][rg] + b1;
          const float h2 = hbuf[row * 64 + fl];
          as_buf[(size_t)(m0 + row) * 2048 + f0 + fl] = f2bf(gelu_exact(h2) * h1 * mv);
        }
    }
  }
}

// ---------------- expert fc2 ----------------
__global__ __launch_bounds__(256) void k_exp_fc2(const short* __restrict__ a_buf,
    const float* __restrict__ fc2_w, const float* __restrict__ fc2_b,
    const int* __restrict__ cnt, const int* __restrict__ offs,
    const float* __restrict__ row_wt, short* __restrict__ yexp)
{
  int e, lt;
  if (!resolve_tile128(cnt, blockIdx.y, e, lt)) return;
  __shared__ short smem[2 * 128 * LDA];
  short* As = smem;
  short* Bs = smem + 128 * LDA;
  const int tid = threadIdx.x;
  const int d0 = blockIdx.x * 128;
  const int rowBase = offs[e] + lt * 128;
  int nrows = cnt[e] - lt * 128; if (nrows > 128) nrows = 128;
  const int lane = tid & 63, ml = lane & 15, kq = lane >> 4;
  const int wr = (tid >> 6) >> 1, wc = (tid >> 6) & 1;
  const int r0 = tid >> 3, c = tid & 7;
  const float* wbase = fc2_w + (size_t)e * 1024 * 1024;
  const short* aP[4]; const float* bP[4];
#pragma unroll
  for (int i = 0; i < 4; i++) {
    int r = r0 + 32 * i;
    aP[i] = a_buf + (size_t)(rowBase + r) * 1024 + c * 8;
    bP[i] = wbase + (size_t)(d0 + r) * 1024 + c * 8;
  }
  f32x4 acc[4][4] = {};
  for (int k0 = 0; k0 < 1024; k0 += 64) {
#pragma unroll
    for (int i = 0; i < 4; i++) {
      int r = r0 + 32 * i;
      *(int4*)&As[r * LDA + c * 8] = *(const int4*)(aP[i] + k0);
      float4 lo = *(const float4*)(bP[i] + k0);
      float4 hi = *(const float4*)(bP[i] + k0 + 4);
      Pack8 pk;
      pk.s[0] = f2bf(lo.x); pk.s[1] = f2bf(lo.y); pk.s[2] = f2bf(lo.z); pk.s[3] = f2bf(lo.w);
      pk.s[4] = f2bf(hi.x); pk.s[5] = f2bf(hi.y); pk.s[6] = f2bf(hi.z); pk.s[7] = f2bf(hi.w);
      *(int4*)&Bs[r * LDA + c * 8] = pk.v;
    }
    __syncthreads();
#pragma unroll
    for (int kk = 0; kk < 2; kk++) {
      const int kbase = kk * 32 + kq * 8;
      bfrag a[4], bb[4];
#pragma unroll
      for (int i = 0; i < 4; i++) a[i] = *(bfrag*)&As[(wr * 64 + i * 16 + ml) * LDA + kbase];
#pragma unroll
      for (int j = 0; j < 4; j++) bb[j] = *(bfrag*)&Bs[(wc * 64 + j * 16 + ml) * LDA + kbase];
#pragma unroll
      for (int i = 0; i < 4; i++)
#pragma unroll
        for (int j = 0; j < 4; j++)
          acc[i][j] = __builtin_amdgcn_mfma_f32_16x16x32_bf16(a[i], bb[j], acc[i][j], 0, 0, 0);
    }
    __syncthreads();
  }
#pragma unroll
  for (int j = 0; j < 4; j++) {
    const int d = d0 + wc * 64 + j * 16 + ml;
    const float bv = fc2_b[(size_t)e * 1024 + d];
#pragma unroll
    for (int i = 0; i < 4; i++)
#pragma unroll
      for (int rg = 0; rg < 4; rg++) {
        const int row = wr * 64 + i * 16 + kq * 4 + rg;
        if (row < nrows) {
          const float wt = row_wt[rowBase + row];
          yexp[(size_t)(rowBase + row) * 1024 + d] = f2bf((acc[i][j][rg] + bv) * wt);
        }
      }
  }
}

// ---------------- shared fc2 (writes y f32, full coverage) ----------------
__global__ __launch_bounds__(256) void k_shared_fc2(const short* __restrict__ as_buf,
    const float* __restrict__ w, const float* __restrict__ b, float* __restrict__ y)
{
  __shared__ short smem[2 * 128 * LDA];
  short* As = smem;
  short* Bs = smem + 128 * LDA;
  const int tid = threadIdx.x;
  const int d0 = blockIdx.x * 128;
  const int m0 = blockIdx.y * 128;
  const int lane = tid & 63, ml = lane & 15, kq = lane >> 4;
  const int wr = (tid >> 6) >> 1, wc = (tid >> 6) & 1;
  const int r0 = tid >> 3, c = tid & 7;
  const short* aP[4]; const float* bP[4];
#pragma unroll
  for (int i = 0; i < 4; i++) {
    int r = r0 + 32 * i;
    aP[i] = as_buf + (size_t)(m0 + r) * 2048 + c * 8;
    bP[i] = w + (size_t)(d0 + r) * 2048 + c * 8;
  }
  f32x4 acc[4][4] = {};
  for (int k0 = 0; k0 < 2048; k0 += 64) {
#pragma unroll
    for (int i = 0; i < 4; i++) {
      int r = r0 + 32 * i;
      *(int4*)&As[r * LDA + c * 8] = *(const int4*)(aP[i] + k0);
      float4 lo = *(const float4*)(bP[i] + k0);
      float4 hi = *(const float4*)(bP[i] + k0 + 4);
      Pack8 pk;
      pk.s[0] = f2bf(lo.x); pk.s[1] = f2bf(lo.y); pk.s[2] = f2bf(lo.z); pk.s[3] = f2bf(lo.w);
      pk.s[4] = f2bf(hi.x); pk.s[5] = f2bf(hi.y); pk.s[6] = f2bf(hi.z); pk.s[7] = f2bf(hi.w);
      *(int4*)&Bs[r * LDA + c * 8] = pk.v;
    }
    __syncthreads();
#pragma unroll
    for (int kk = 0; kk < 2; kk++) {
      const int kbase = kk * 32 + kq * 8;
      bfrag a[4], bb[4];
#pragma unroll
      for (int i = 0; i < 4; i++) a[i] = *(bfrag*)&As[(wr * 64 + i * 16 + ml) * LDA + kbase];
#pragma unroll
      for (int j = 0; j < 4; j++) bb[j] = *(bfrag*)&Bs[(wc * 64 + j * 16 + ml) * LDA + kbase];
#pragma unroll
      for (int i = 0; i < 4; i++)
#pragma unroll
        for (int j = 0; j < 4; j++)
          acc[i][j] = __builtin_amdgcn_mfma_f32_16x16x32_bf16(a[i], bb[j], acc[i][j], 0, 0, 0);
    }
    __syncthreads();
  }
#pragma unroll
  for (int j = 0; j < 4; j++) {
    const int d = d0 + wc * 64 + j * 16 + ml;
    const float bv = b[d];
#pragma unroll
    for (int i = 0; i < 4; i++)
#pragma unroll
      for (int rg = 0; rg < 4; rg++) {
        const int row = wr * 64 + i * 16 + kq * 4 + rg;
        y[(size_t)(m0 + row) * 1024 + d] = acc[i][j][rg] + bv;
      }
  }
}

// ---------------- combine ----------------
__global__ __launch_bounds__(256) void k_combine(float* __restrict__ y,
    const short* __restrict__ yexp, const int* __restrict__ row_id)
{
  const int idx = blockIdx.x * 256 + threadIdx.x;
  const int t = idx >> 8;
  const int d4 = (idx & 255) * 4;
  const int r0 = row_id[t * 3], r1 = row_id[t * 3 + 1], r2 = row_id[t * 3 + 2];
  float4 acc = *(float4*)(y + (size_t)t * 1024 + d4);
  const ushort4 v0 = *(const ushort4*)(yexp + (size_t)r0 * 1024 + d4);
  const ushort4 v1 = *(const ushort4*)(yexp + (size_t)r1 * 1024 + d4);
  const ushort4 v2 = *(const ushort4*)(yexp + (size_t)r2 * 1024 + d4);
  acc.x += bf2f(v0.x) + bf2f(v1.x) + bf2f(v2.x);
  acc.y += bf2f(v0.y) + bf2f(v1.y) + bf2f(v2.y);
  acc.z += bf2f(v0.z) + bf2f(v1.z) + bf2f(v2.z);
  acc.w += bf2f(v0.w) + bf2f(v1.w) + bf2f(v2.w);
  *(float4*)(y + (size_t)t * 1024 + d4) = acc;
}

extern "C" void kernel_launch(void* const* d_in, const int* in_sizes, int n_in,
                              void* d_out, int out_size, void* d_ws, size_t ws_size,
                              hipStream_t stream) {
  const float* x          = (const float*)d_in[0];
  const float* gate_w     = (const float*)d_in[1];
  const float* fc1_w      = (const float*)d_in[2];
  const float* fc1_b      = (const float*)d_in[3];
  const float* geglu_mult = (const float*)d_in[4];
  const float* fc2_w      = (const float*)d_in[5];
  const float* fc2_b      = (const float*)d_in[6];
  const float* s_fc1_w    = (const float*)d_in[7];
  const float* s_fc1_b    = (const float*)d_in[8];
  const float* s_mult     = (const float*)d_in[9];
  const float* s_fc2_w    = (const float*)d_in[10];
  const float* s_fc2_b    = (const float*)d_in[11];
  float* y = (float*)d_out;

  char* wsb = (char*)d_ws;
  int*   cnt      = (int*)(wsb + 0);
  int*   offs     = (int*)(wsb + 64);
  int*   topk_idx = (int*)(wsb + 256);
  float* topk_w   = (float*)(wsb + 24832);
  int*   row_tok  = (int*)(wsb + 49408);
  float* row_wt   = (float*)(wsb + 74496);
  int*   row_id   = (int*)(wsb + 99584);
  short* xbf      = (short*)(wsb + 131072);               // 2048x1024 bf16 (4 MB)
  short* a_buf    = (short*)(wsb + 4325376);              // union: a_buf (6272x1024) / as_buf (2048x2048)
  short* as_buf   = (short*)(wsb + 4325376);
  short* yexp     = (short*)(wsb + 17170432);             // 6272x1024 bf16
  // total ~30.0 MB

  k_convert_x<<<2048, 256, 0, stream>>>(x, xbf);
  k_gate<<<512, 64, 0, stream>>>(x, gate_w, topk_idx, topk_w);
  k_route<<<1, 1024, 0, stream>>>(topk_idx, topk_w, cnt, offs, row_tok, row_wt, row_id);
  // shared path first (as_buf shares storage with a_buf)
  k_shared_fc1<<<dim3(32, 16), 256, 0, stream>>>(xbf, s_fc1_w, s_fc1_b, s_mult, as_buf);
  k_shared_fc2<<<dim3(8, 16), 256, 0, stream>>>(as_buf, s_fc2_w, s_fc2_b, y);
  // expert path
  k_exp_fc1<<<dim3(16, 63), 256, 0, stream>>>(xbf, fc1_w, fc1_b, geglu_mult, cnt, offs, row_tok, a_buf);
  k_exp_fc2<<<dim3(8, 63), 256, 0, stream>>>(a_buf, fc2_w, fc2_b, cnt, offs, row_wt, yexp);
  k_combine<<<2048, 256, 0, stream>>>(y, yexp, row_id);
}

// Round 3
// 484.855 us; speedup vs baseline: 1.4830x; 1.2355x over previous
//
#include <hip/hip_runtime.h>

typedef __attribute__((ext_vector_type(8))) short bfrag;
typedef __attribute__((ext_vector_type(4))) float f32x4;

__device__ __forceinline__ short f2bf(float f) {
  union { float f; unsigned u; } v; v.f = f;
  unsigned r = v.u + 0x7FFFu + ((v.u >> 16) & 1u);  // RNE
  return (short)(r >> 16);
}
__device__ __forceinline__ float bf2f(unsigned short h) {
  union { unsigned u; float f; } v; v.u = ((unsigned)h) << 16;
  return v.f;
}
__device__ __forceinline__ float gelu_exact(float g) {
  return 0.5f * g * (1.0f + erff(g * 0.70710678118654752f));
}
__device__ __forceinline__ void gld_lds16(const short* g, short* l) {
  __builtin_amdgcn_global_load_lds(
      (const __attribute__((address_space(1))) void*)g,
      (__attribute__((address_space(3))) void*)l, 16, 0, 0);
}

// ---------------- weights -> bf16 (all four weight tensors) ----------------
// segments (float4 counts): fc1 7864320 | fc2 3932160 | sfc1 1048576 | sfc2 524288
__global__ __launch_bounds__(256) void k_convert_w(
    const float* __restrict__ s0, const float* __restrict__ s1,
    const float* __restrict__ s2, const float* __restrict__ s3,
    short* __restrict__ d0, short* __restrict__ d1,
    short* __restrict__ d2, short* __restrict__ d3)
{
  long base = (long)blockIdx.x * 1024 + threadIdx.x;  // 4 float4 per thread
#pragma unroll
  for (int j = 0; j < 4; j++) {
    long idx = base + j * 256;
    const float* s; short* d; long r = idx;
    if (r < 7864320L) { s = s0; d = d0; }
    else if ((r -= 7864320L) < 3932160L) { s = s1; d = d1; }
    else if ((r -= 3932160L) < 1048576L) { s = s2; d = d2; }
    else { r -= 1048576L; s = s3; d = d3; }
    const float4 v = ((const float4*)s)[r];
    ((short4*)d)[r] = make_short4(f2bf(v.x), f2bf(v.y), f2bf(v.z), f2bf(v.w));
  }
}

// ---------------- gating (4 tokens/wave) + x->bf16 fused ----------------
__global__ __launch_bounds__(64) void k_gate(const float* __restrict__ x,
    const float* __restrict__ gw, int* __restrict__ topk_idx,
    float* __restrict__ topk_w, short* __restrict__ xbf)
{
  const int t0 = blockIdx.x * 4;
  const int lane = threadIdx.x;
  float xv[4][16];
#pragma unroll
  for (int tt = 0; tt < 4; tt++)
#pragma unroll
    for (int i = 0; i < 16; i++) {
      xv[tt][i] = x[(size_t)(t0 + tt) * 1024 + lane + 64 * i];
      xbf[(size_t)(t0 + tt) * 1024 + lane + 64 * i] = f2bf(xv[tt][i]);
    }
  float p[4][15];
#pragma unroll
  for (int e = 0; e < 15; e++) {
    float wv[16];
#pragma unroll
    for (int i = 0; i < 16; i++) wv[i] = gw[(size_t)e * 1024 + lane + 64 * i];
#pragma unroll
    for (int tt = 0; tt < 4; tt++) {
      float s = 0.f;
#pragma unroll
      for (int i = 0; i < 16; i++) s += xv[tt][i] * wv[i];
#pragma unroll
      for (int o = 32; o; o >>= 1) s += __shfl_xor(s, o, 64);
      p[tt][e] = s;
    }
  }
#pragma unroll
  for (int tt = 0; tt < 4; tt++) {
    float m = -1e30f;
#pragma unroll
    for (int e = 0; e < 15; e++) m = fmaxf(m, p[tt][e]);
    float q[15], Z = 0.f;
#pragma unroll
    for (int e = 0; e < 15; e++) { q[e] = expf(p[tt][e] - m); Z += q[e]; }
    int usedMask = 0; int bi[3]; float bv[3];
#pragma unroll
    for (int j = 0; j < 3; j++) {
      float best = -1.f; int b = 0;
#pragma unroll
      for (int e = 0; e < 15; e++) {
        bool ok = (!((usedMask >> e) & 1)) && (q[e] > best);
        if (ok) { best = q[e]; b = e; }
      }
      bi[j] = b; bv[j] = best / Z; usedMask |= 1 << b;
    }
    if (lane == tt) {
      float den = bv[0] + bv[1] + bv[2] + 1e-20f;
#pragma unroll
      for (int j = 0; j < 3; j++) {
        topk_idx[(t0 + tt) * 3 + j] = bi[j];
        topk_w[(t0 + tt) * 3 + j] = bv[j] / den;
      }
    }
  }
}

// ---------------- routing: single block, LDS atomics ----------------
__global__ __launch_bounds__(1024) void k_route(const int* __restrict__ topk_idx,
    const float* __restrict__ topk_w, int* __restrict__ cnt_g, int* __restrict__ offs_g,
    int* __restrict__ row_tok, float* __restrict__ row_wt, int* __restrict__ row_id)
{
  __shared__ int scnt[16], soffs[16], sfill[16];
  const int tid = threadIdx.x;
  if (tid < 16) { scnt[tid] = 0; sfill[tid] = 0; }
  __syncthreads();
  for (int i = tid; i < 6144; i += 1024) atomicAdd(&scnt[topk_idx[i]], 1);
  __syncthreads();
  if (tid == 0) {
    int a = 0;
    for (int e = 0; e < 15; e++) { soffs[e] = a; offs_g[e] = a; cnt_g[e] = scnt[e]; a += scnt[e]; }
  }
  __syncthreads();
  for (int i = tid; i < 6144; i += 1024) {
    int e = topk_idx[i];
    int pos = atomicAdd(&sfill[e], 1);
    int row = soffs[e] + pos;
    row_tok[row] = i / 3;
    row_wt[row] = topk_w[i];
    row_id[i] = row;
  }
}

__device__ __forceinline__ bool resolve_tile128(const int* __restrict__ cnt, int ty,
                                                int& e, int& lt) {
  int acc = 0;
#pragma unroll
  for (int i = 0; i < 15; i++) {
    int tl = (cnt[i] + 127) >> 7;
    if (ty < acc + tl) { e = i; lt = ty - acc; return true; }
    acc += tl;
  }
  return false;
}

// ============== unified fc1 (+geglu): shared blocks [0,512), expert [512,1520) ==============
// 128(M) x 64(F) tile; B-tile = 128 rows (0-63: h1 rows, 64-127: h2 rows); K=1024, BK=64.
// LDS: unpadded 128x64 bf16 tiles, 16B chunks XOR-swizzled: slot = chunk ^ (row&7).
__global__ __launch_bounds__(256) void k_fc1(
    const short* __restrict__ xbf,
    const short* __restrict__ wsh, const float* __restrict__ bsh, const float* __restrict__ msh,
    const short* __restrict__ wex, const float* __restrict__ bex, const float* __restrict__ mex,
    const int* __restrict__ cnt, const int* __restrict__ offs, const int* __restrict__ row_tok,
    short* __restrict__ as_buf, short* __restrict__ a_buf)
{
  __shared__ short smem[2 * 128 * 64];  // 32 KB
  short* As = smem;
  short* Bs = smem + 128 * 64;
  const int tid = threadIdx.x;
  const int bid = blockIdx.x;
  const bool sh = bid < 512;
  int f0, m0 = 0, e = 0, rowBase = 0, nrows = 128;
  if (sh) {
    f0 = (bid & 31) * 64; m0 = (bid >> 5) * 128;
  } else {
    const int b2 = bid - 512;
    int lt;
    if (!resolve_tile128(cnt, b2 >> 4, e, lt)) return;
    f0 = (b2 & 15) * 64;
    rowBase = offs[e] + lt * 128;
    nrows = cnt[e] - lt * 128; if (nrows > 128) nrows = 128;
  }
  const int lane = tid & 63, ml = lane & 15, kq = lane >> 4, mlo = lane & 7;
  const int wv = tid >> 6, wr = wv >> 1, wc = wv & 1;
  const int lrow = lane >> 3, lchk = lane & 7;
  const int Fhalf = sh ? 2048 : 1024;
  const short* wptr = sh ? wsh : (wex + (size_t)e * 2048 * 1024);
  const short* aSrc[4]; const short* bSrc[4];
#pragma unroll
  for (int t = 0; t < 4; t++) {
    const int r = wv * 32 + t * 8 + lrow;
    const int sc = (lchk ^ (r & 7)) * 8;
    if (sh) aSrc[t] = xbf + (size_t)(m0 + r) * 1024 + sc;
    else {
      const int rc = r < nrows ? r : nrows - 1;
      aSrc[t] = xbf + (size_t)row_tok[rowBase + rc] * 1024 + sc;
    }
    const int grow = (r < 64) ? (f0 + r) : (Fhalf + f0 + r - 64);
    bSrc[t] = wptr + (size_t)grow * 1024 + sc;
  }
  f32x4 acc[4][4] = {};
  for (int k0 = 0; k0 < 1024; k0 += 64) {
#pragma unroll
    for (int t = 0; t < 4; t++) gld_lds16(aSrc[t] + k0, As + (wv * 32 + t * 8) * 64);
#pragma unroll
    for (int t = 0; t < 4; t++) gld_lds16(bSrc[t] + k0, Bs + (wv * 32 + t * 8) * 64);
    __syncthreads();
#pragma unroll
    for (int kk = 0; kk < 2; kk++) {
      const int so = ((kk * 4 + kq) ^ mlo) * 8;
      bfrag af[4], bf[4];
#pragma unroll
      for (int i = 0; i < 4; i++) af[i] = *(bfrag*)&As[(wr * 64 + i * 16 + ml) * 64 + so];
#pragma unroll
      for (int j = 0; j < 4; j++) bf[j] = *(bfrag*)&Bs[(wc * 64 + j * 16 + ml) * 64 + so];
#pragma unroll
      for (int i = 0; i < 4; i++)
#pragma unroll
        for (int j = 0; j < 4; j++)
          acc[i][j] = __builtin_amdgcn_mfma_f32_16x16x32_bf16(af[i], bf[j], acc[i][j], 0, 0, 0);
    }
    __syncthreads();
  }
  // geglu: wc==1 holds h2, exchange via LDS (reuse smem as 128x64 f32 = 32KB)
  float* hbuf = (float*)smem;
  const float* bias = sh ? bsh : (bex + (size_t)e * 2048);
  const float* mult = sh ? msh : (mex + (size_t)e * 1024);
  if (wc == 1) {
#pragma unroll
    for (int j = 0; j < 4; j++) {
      const int fl = j * 16 + ml;
      const float b2 = bias[Fhalf + f0 + fl];
#pragma unroll
      for (int i = 0; i < 4; i++)
#pragma unroll
        for (int rg = 0; rg < 4; rg++) {
          const int row = wr * 64 + i * 16 + kq * 4 + rg;
          hbuf[row * 64 + fl] = acc[i][j][rg] + b2;
        }
    }
  }
  __syncthreads();
  if (wc == 0) {
#pragma unroll
    for (int j = 0; j < 4; j++) {
      const int fl = j * 16 + ml;
      const float b1 = bias[f0 + fl];
      const float mv = mult[f0 + fl];
#pragma unroll
      for (int i = 0; i < 4; i++)
#pragma unroll
        for (int rg = 0; rg < 4; rg++) {
          const int row = wr * 64 + i * 16 + kq * 4 + rg;
          const float h1 = acc[i][j][rg] + b1;
          const float h2 = hbuf[row * 64 + fl];
          const short o = f2bf(gelu_exact(h2) * h1 * mv);
          if (sh) as_buf[(size_t)(m0 + row) * 2048 + f0 + fl] = o;
          else if (row < nrows) a_buf[(size_t)(rowBase + row) * 1024 + f0 + fl] = o;
        }
    }
  }
}

// ============== unified fc2: shared blocks [0,128), expert [128,632) ==============
// 128(M) x 128(D) tile
__global__ __launch_bounds__(256) void k_fc2(
    const short* __restrict__ as_buf, const short* __restrict__ wsfc2, const float* __restrict__ s_b,
    const short* __restrict__ a_buf, const short* __restrict__ wfc2, const float* __restrict__ e_b,
    const int* __restrict__ cnt, const int* __restrict__ offs, const float* __restrict__ row_wt,
    float* __restrict__ y, short* __restrict__ yexp)
{
  __shared__ short smem[2 * 128 * 64];
  short* As = smem;
  short* Bs = smem + 128 * 64;
  const int tid = threadIdx.x;
  const int bid = blockIdx.x;
  const bool sh = bid < 128;
  int d0, m0 = 0, e = 0, rowBase = 0, nrows = 128, Klen, astr, bstr;
  const short *aBase, *bBase;
  if (sh) {
    d0 = (bid & 7) * 128; m0 = (bid >> 3) * 128;
    Klen = 2048; astr = 2048; bstr = 2048;
    aBase = as_buf; bBase = wsfc2;
  } else {
    const int b2 = bid - 128;
    int lt;
    if (!resolve_tile128(cnt, b2 >> 3, e, lt)) return;
    d0 = (b2 & 7) * 128;
    rowBase = offs[e] + lt * 128;
    nrows = cnt[e] - lt * 128; if (nrows > 128) nrows = 128;
    Klen = 1024; astr = 1024; bstr = 1024;
    aBase = a_buf + (size_t)rowBase * 1024;
    bBase = wfc2 + (size_t)e * 1024 * 1024;
  }
  const int lane = tid & 63, ml = lane & 15, kq = lane >> 4, mlo = lane & 7;
  const int wv = tid >> 6, wr = wv >> 1, wc = wv & 1;
  const int lrow = lane >> 3, lchk = lane & 7;
  const short* aSrc[4]; const short* bSrc[4];
#pragma unroll
  for (int t = 0; t < 4; t++) {
    const int r = wv * 32 + t * 8 + lrow;
    const int sc = (lchk ^ (r & 7)) * 8;
    aSrc[t] = aBase + (size_t)(sh ? (m0 + r) : r) * astr + sc;
    bSrc[t] = bBase + (size_t)(d0 + r) * bstr + sc;
  }
  f32x4 acc[4][4] = {};
  for (int k0 = 0; k0 < Klen; k0 += 64) {
#pragma unroll
    for (int t = 0; t < 4; t++) gld_lds16(aSrc[t] + k0, As + (wv * 32 + t * 8) * 64);
#pragma unroll
    for (int t = 0; t < 4; t++) gld_lds16(bSrc[t] + k0, Bs + (wv * 32 + t * 8) * 64);
    __syncthreads();
#pragma unroll
    for (int kk = 0; kk < 2; kk++) {
      const int so = ((kk * 4 + kq) ^ mlo) * 8;
      bfrag af[4], bf[4];
#pragma unroll
      for (int i = 0; i < 4; i++) af[i] = *(bfrag*)&As[(wr * 64 + i * 16 + ml) * 64 + so];
#pragma unroll
      for (int j = 0; j < 4; j++) bf[j] = *(bfrag*)&Bs[(wc * 64 + j * 16 + ml) * 64 + so];
#pragma unroll
      for (int i = 0; i < 4; i++)
#pragma unroll
        for (int j = 0; j < 4; j++)
          acc[i][j] = __builtin_amdgcn_mfma_f32_16x16x32_bf16(af[i], bf[j], acc[i][j], 0, 0, 0);
    }
    __syncthreads();
  }
#pragma unroll
  for (int j = 0; j < 4; j++) {
    const int d = d0 + wc * 64 + j * 16 + ml;
    const float bv = sh ? s_b[d] : e_b[(size_t)e * 1024 + d];
#pragma unroll
    for (int i = 0; i < 4; i++)
#pragma unroll
      for (int rg = 0; rg < 4; rg++) {
        const int row = wr * 64 + i * 16 + kq * 4 + rg;
        if (sh) {
          y[(size_t)(m0 + row) * 1024 + d] = acc[i][j][rg] + bv;
        } else if (row < nrows) {
          const float wt = row_wt[rowBase + row];
          yexp[(size_t)(rowBase + row) * 1024 + d] = f2bf((acc[i][j][rg] + bv) * wt);
        }
      }
  }
}

// ---------------- combine ----------------
__global__ __launch_bounds__(256) void k_combine(float* __restrict__ y,
    const short* __restrict__ yexp, const int* __restrict__ row_id)
{
  const int idx = blockIdx.x * 256 + threadIdx.x;
  const int t = idx >> 8;
  const int d4 = (idx & 255) * 4;
  const int r0 = row_id[t * 3], r1 = row_id[t * 3 + 1], r2 = row_id[t * 3 + 2];
  float4 acc = *(float4*)(y + (size_t)t * 1024 + d4);
  const ushort4 v0 = *(const ushort4*)(yexp + (size_t)r0 * 1024 + d4);
  const ushort4 v1 = *(const ushort4*)(yexp + (size_t)r1 * 1024 + d4);
  const ushort4 v2 = *(const ushort4*)(yexp + (size_t)r2 * 1024 + d4);
  acc.x += bf2f(v0.x) + bf2f(v1.x) + bf2f(v2.x);
  acc.y += bf2f(v0.y) + bf2f(v1.y) + bf2f(v2.y);
  acc.z += bf2f(v0.z) + bf2f(v1.z) + bf2f(v2.z);
  acc.w += bf2f(v0.w) + bf2f(v1.w) + bf2f(v2.w);
  *(float4*)(y + (size_t)t * 1024 + d4) = acc;
}

extern "C" void kernel_launch(void* const* d_in, const int* in_sizes, int n_in,
                              void* d_out, int out_size, void* d_ws, size_t ws_size,
                              hipStream_t stream) {
  const float* x          = (const float*)d_in[0];
  const float* gate_w     = (const float*)d_in[1];
  const float* fc1_w      = (const float*)d_in[2];
  const float* fc1_b      = (const float*)d_in[3];
  const float* geglu_mult = (const float*)d_in[4];
  const float* fc2_w      = (const float*)d_in[5];
  const float* fc2_b      = (const float*)d_in[6];
  const float* s_fc1_w    = (const float*)d_in[7];
  const float* s_fc1_b    = (const float*)d_in[8];
  const float* s_mult     = (const float*)d_in[9];
  const float* s_fc2_w    = (const float*)d_in[10];
  const float* s_fc2_b    = (const float*)d_in[11];
  float* y = (float*)d_out;

  char* wsb = (char*)d_ws;
  int*   cnt      = (int*)(wsb + 0);
  int*   offs     = (int*)(wsb + 64);
  int*   topk_idx = (int*)(wsb + 256);
  float* topk_w   = (float*)(wsb + 24832);
  int*   row_tok  = (int*)(wsb + 49408);
  float* row_wt   = (float*)(wsb + 74496);
  int*   row_id   = (int*)(wsb + 99584);
  short* xbf      = (short*)(wsb + 131072);       // 2048x1024        (8.39 MB)
  short* a_buf    = (short*)(wsb + 8519680);      // 6272x1024        (12.85 MB)
  short* as_buf   = (short*)(wsb + 21364736);     // 2048x2048        (8.39 MB)
  short* yexp     = (short*)(wsb + 29753344);     // 6272x1024        (12.85 MB)
  short* wbf_sfc1 = (short*)(wsb + 42598400);     // 4096x1024        (8.39 MB)
  short* wbf_sfc2 = (short*)(wsb + 50987008);     // 1024x2048        (4.19 MB)
  short* wbf_fc1  = (short*)(wsb + 55181312);     // 15x2048x1024     (62.91 MB)
  short* wbf_fc2  = (short*)(wsb + 118095872);    // 15x1024x1024     (31.46 MB)
  // total ~149.6 MB

  k_convert_w<<<13056, 256, 0, stream>>>(fc1_w, fc2_w, s_fc1_w, s_fc2_w,
                                         wbf_fc1, wbf_fc2, wbf_sfc1, wbf_sfc2);
  k_gate<<<512, 64, 0, stream>>>(x, gate_w, topk_idx, topk_w, xbf);
  k_route<<<1, 1024, 0, stream>>>(topk_idx, topk_w, cnt, offs, row_tok, row_wt, row_id);
  k_fc1<<<1520, 256, 0, stream>>>(xbf, wbf_sfc1, s_fc1_b, s_mult,
                                  wbf_fc1, fc1_b, geglu_mult,
                                  cnt, offs, row_tok, as_buf, a_buf);
  k_fc2<<<632, 256, 0, stream>>>(as_buf, wbf_sfc2, s_fc2_b,
                                 a_buf, wbf_fc2, fc2_b,
                                 cnt, offs, row_wt, y, yexp);
  k_combine<<<2048, 256, 0, stream>>>(y, yexp, row_id);
}

// Round 4
// 458.235 us; speedup vs baseline: 1.5692x; 1.0581x over previous
//
#include <hip/hip_runtime.h>

typedef __attribute__((ext_vector_type(8))) short bfrag;
typedef __attribute__((ext_vector_type(4))) float f32x4;

__device__ __forceinline__ short f2bf(float f) {
  union { float f; unsigned u; } v; v.f = f;
  unsigned r = v.u + 0x7FFFu + ((v.u >> 16) & 1u);  // RNE
  return (short)(r >> 16);
}
__device__ __forceinline__ float bf2f(unsigned short h) {
  union { unsigned u; float f; } v; v.u = ((unsigned)h) << 16;
  return v.f;
}
__device__ __forceinline__ float gelu_exact(float g) {
  return 0.5f * g * (1.0f + erff(g * 0.70710678118654752f));
}
__device__ __forceinline__ void gld_lds16(const short* g, short* l) {
  __builtin_amdgcn_global_load_lds(
      (const __attribute__((address_space(1))) void*)g,
      (__attribute__((address_space(3))) void*)l, 16, 0, 0);
}

// ---------------- weights -> bf16, block-uniform segments, pure BW ----------------
// float4 counts: fc1 7864320 (1920 blk) | fc2 3932160 (960) | sfc1 1048576 (256) | sfc2 524288 (128)
__global__ __launch_bounds__(256) void k_convert_w(
    const float* __restrict__ s0, const float* __restrict__ s1,
    const float* __restrict__ s2, const float* __restrict__ s3,
    short* __restrict__ d0, short* __restrict__ d1,
    short* __restrict__ d2, short* __restrict__ d3)
{
  const int b = blockIdx.x;
  const float* s; short* d; long off;
  if (b < 1920)      { s = s0; d = d0; off = (long)b * 4096; }
  else if (b < 2880) { s = s1; d = d1; off = (long)(b - 1920) * 4096; }
  else if (b < 3136) { s = s2; d = d2; off = (long)(b - 2880) * 4096; }
  else               { s = s3; d = d3; off = (long)(b - 3136) * 4096; }
#pragma unroll
  for (int j = 0; j < 16; j++) {
    const long i = off + j * 256 + threadIdx.x;
    const float4 v = ((const float4*)s)[i];
    ((short4*)d)[i] = make_short4(f2bf(v.x), f2bf(v.y), f2bf(v.z), f2bf(v.w));
  }
}

// ---------------- gating (4 tokens/wave) + x->bf16 fused ----------------
__global__ __launch_bounds__(64) void k_gate(const float* __restrict__ x,
    const float* __restrict__ gw, int* __restrict__ topk_idx,
    float* __restrict__ topk_w, short* __restrict__ xbf)
{
  const int t0 = blockIdx.x * 4;
  const int lane = threadIdx.x;
  float xv[4][16];
#pragma unroll
  for (int tt = 0; tt < 4; tt++)
#pragma unroll
    for (int i = 0; i < 16; i++) {
      xv[tt][i] = x[(size_t)(t0 + tt) * 1024 + lane + 64 * i];
      xbf[(size_t)(t0 + tt) * 1024 + lane + 64 * i] = f2bf(xv[tt][i]);
    }
  float p[4][15];
#pragma unroll
  for (int e = 0; e < 15; e++) {
    float wv[16];
#pragma unroll
    for (int i = 0; i < 16; i++) wv[i] = gw[(size_t)e * 1024 + lane + 64 * i];
#pragma unroll
    for (int tt = 0; tt < 4; tt++) {
      float s = 0.f;
#pragma unroll
      for (int i = 0; i < 16; i++) s += xv[tt][i] * wv[i];
#pragma unroll
      for (int o = 32; o; o >>= 1) s += __shfl_xor(s, o, 64);
      p[tt][e] = s;
    }
  }
#pragma unroll
  for (int tt = 0; tt < 4; tt++) {
    float m = -1e30f;
#pragma unroll
    for (int e = 0; e < 15; e++) m = fmaxf(m, p[tt][e]);
    float q[15], Z = 0.f;
#pragma unroll
    for (int e = 0; e < 15; e++) { q[e] = expf(p[tt][e] - m); Z += q[e]; }
    int usedMask = 0; int bi[3]; float bv[3];
#pragma unroll
    for (int j = 0; j < 3; j++) {
      float best = -1.f; int b = 0;
#pragma unroll
      for (int e = 0; e < 15; e++) {
        bool ok = (!((usedMask >> e) & 1)) && (q[e] > best);
        if (ok) { best = q[e]; b = e; }
      }
      bi[j] = b; bv[j] = best / Z; usedMask |= 1 << b;
    }
    if (lane == tt) {
      float den = bv[0] + bv[1] + bv[2] + 1e-20f;
#pragma unroll
      for (int j = 0; j < 3; j++) {
        topk_idx[(t0 + tt) * 3 + j] = bi[j];
        topk_w[(t0 + tt) * 3 + j] = bv[j] / den;
      }
    }
  }
}

// ---------------- routing: single block, LDS atomics ----------------
__global__ __launch_bounds__(1024) void k_route(const int* __restrict__ topk_idx,
    const float* __restrict__ topk_w, int* __restrict__ cnt_g, int* __restrict__ offs_g,
    int* __restrict__ row_tok, float* __restrict__ row_wt, int* __restrict__ row_id)
{
  __shared__ int scnt[16], soffs[16], sfill[16];
  const int tid = threadIdx.x;
  if (tid < 16) { scnt[tid] = 0; sfill[tid] = 0; }
  __syncthreads();
  for (int i = tid; i < 6144; i += 1024) atomicAdd(&scnt[topk_idx[i]], 1);
  __syncthreads();
  if (tid == 0) {
    int a = 0;
    for (int e = 0; e < 15; e++) { soffs[e] = a; offs_g[e] = a; cnt_g[e] = scnt[e]; a += scnt[e]; }
  }
  __syncthreads();
  for (int i = tid; i < 6144; i += 1024) {
    int e = topk_idx[i];
    int pos = atomicAdd(&sfill[e], 1);
    int row = soffs[e] + pos;
    row_tok[row] = i / 3;
    row_wt[row] = topk_w[i];
    row_id[i] = row;
  }
}

__device__ __forceinline__ bool resolve_tile128(const int* __restrict__ cnt, int ty,
                                                int& e, int& lt) {
  int acc = 0;
#pragma unroll
  for (int i = 0; i < 15; i++) {
    int tl = (cnt[i] + 127) >> 7;
    if (ty < acc + tl) { e = i; lt = ty - acc; return true; }
    acc += tl;
  }
  return false;
}

// ============== unified fc1 (+geglu): shared blocks [0,512), expert [512,1520) ==============
// 128(M) x 64(F) tile, B-tile 128 rows (0-63 h1, 64-127 h2 for the SAME f columns).
// Fragment remap: wave (wr,wc) computes M rows wr*64..+63, f-cols wc*32..+31, holding
// h1 in acc[i][0..1] and h2 in acc[i][2..3] -> geglu fully in-register, no LDS exchange.
__global__ __launch_bounds__(256) void k_fc1(
    const short* __restrict__ xbf,
    const short* __restrict__ wsh, const float* __restrict__ bsh, const float* __restrict__ msh,
    const short* __restrict__ wex, const float* __restrict__ bex, const float* __restrict__ mex,
    const int* __restrict__ cnt, const int* __restrict__ offs, const int* __restrict__ row_tok,
    short* __restrict__ as_buf, short* __restrict__ a_buf)
{
  __shared__ short smem[2 * 128 * 64];  // 32 KB
  short* As = smem;
  short* Bs = smem + 128 * 64;
  const int tid = threadIdx.x;
  const int bid = blockIdx.x;
  const bool sh = bid < 512;
  int f0, m0 = 0, e = 0, rowBase = 0, nrows = 128;
  if (sh) {
    f0 = (bid & 31) * 64; m0 = (bid >> 5) * 128;
  } else {
    const int b2 = bid - 512;
    int lt;
    if (!resolve_tile128(cnt, b2 >> 4, e, lt)) return;
    f0 = (b2 & 15) * 64;
    rowBase = offs[e] + lt * 128;
    nrows = cnt[e] - lt * 128; if (nrows > 128) nrows = 128;
  }
  const int lane = tid & 63, ml = lane & 15, kq = lane >> 4, mlo = lane & 7;
  const int wv = tid >> 6, wr = wv >> 1, wc = wv & 1;
  const int lrow = lane >> 3, lchk = lane & 7;
  const int Fhalf = sh ? 2048 : 1024;
  const short* wptr = sh ? wsh : (wex + (size_t)e * 2048 * 1024);
  const short* aSrc[4]; const short* bSrc[4];
#pragma unroll
  for (int t = 0; t < 4; t++) {
    const int r = wv * 32 + t * 8 + lrow;
    const int sc = (lchk ^ (r & 7)) * 8;
    if (sh) aSrc[t] = xbf + (size_t)(m0 + r) * 1024 + sc;
    else {
      const int rc = r < nrows ? r : nrows - 1;
      aSrc[t] = xbf + (size_t)row_tok[rowBase + rc] * 1024 + sc;
    }
    const int grow = (r < 64) ? (f0 + r) : (Fhalf + f0 + r - 64);
    bSrc[t] = wptr + (size_t)grow * 1024 + sc;
  }
  f32x4 acc[4][4] = {};
  for (int k0 = 0; k0 < 1024; k0 += 64) {
#pragma unroll
    for (int t = 0; t < 4; t++) gld_lds16(aSrc[t] + k0, As + (wv * 32 + t * 8) * 64);
#pragma unroll
    for (int t = 0; t < 4; t++) gld_lds16(bSrc[t] + k0, Bs + (wv * 32 + t * 8) * 64);
    __syncthreads();
#pragma unroll
    for (int kk = 0; kk < 2; kk++) {
      const int so = ((kk * 4 + kq) ^ mlo) * 8;
      bfrag af[4], bf[4];
#pragma unroll
      for (int i = 0; i < 4; i++) af[i] = *(bfrag*)&As[(wr * 64 + i * 16 + ml) * 64 + so];
      // j=0,1: h1 rows; j=2,3: h2 rows (same f-columns wc*32 + (j&1)*16 + ml)
#pragma unroll
      for (int j = 0; j < 4; j++) {
        const int brow = ((j >> 1) ? 64 : 0) + wc * 32 + (j & 1) * 16 + ml;
        bf[j] = *(bfrag*)&Bs[brow * 64 + so];
      }
#pragma unroll
      for (int i = 0; i < 4; i++)
#pragma unroll
        for (int j = 0; j < 4; j++)
          acc[i][j] = __builtin_amdgcn_mfma_f32_16x16x32_bf16(af[i], bf[j], acc[i][j], 0, 0, 0);
    }
    __syncthreads();
  }
  // in-register geglu epilogue: 32 outputs/lane, all 4 waves participate
  const float* bias = sh ? bsh : (bex + (size_t)e * 2048);
  const float* mult = sh ? msh : (mex + (size_t)e * 1024);
#pragma unroll
  for (int jj = 0; jj < 2; jj++) {
    const int fl = wc * 32 + jj * 16 + ml;
    const int f = f0 + fl;
    const float b1 = bias[f];
    const float b2 = bias[Fhalf + f];
    const float mv = mult[f];
#pragma unroll
    for (int i = 0; i < 4; i++)
#pragma unroll
      for (int rg = 0; rg < 4; rg++) {
        const int row = wr * 64 + i * 16 + kq * 4 + rg;
        const float h1 = acc[i][jj][rg] + b1;
        const float h2 = acc[i][jj + 2][rg] + b2;
        const short o = f2bf(gelu_exact(h2) * h1 * mv);
        if (sh) as_buf[(size_t)(m0 + row) * 2048 + f] = o;
        else if (row < nrows) a_buf[(size_t)(rowBase + row) * 1024 + f] = o;
      }
  }
}

// ============== unified fc2: shared blocks [0,128), expert [128,632) ==============
// 128(M) x 128(D) tile
__global__ __launch_bounds__(256) void k_fc2(
    const short* __restrict__ as_buf, const short* __restrict__ wsfc2, const float* __restrict__ s_b,
    const short* __restrict__ a_buf, const short* __restrict__ wfc2, const float* __restrict__ e_b,
    const int* __restrict__ cnt, const int* __restrict__ offs, const float* __restrict__ row_wt,
    float* __restrict__ y, short* __restrict__ yexp)
{
  __shared__ short smem[2 * 128 * 64];
  short* As = smem;
  short* Bs = smem + 128 * 64;
  const int tid = threadIdx.x;
  const int bid = blockIdx.x;
  const bool sh = bid < 128;
  int d0, m0 = 0, e = 0, rowBase = 0, nrows = 128, Klen, astr, bstr;
  const short *aBase, *bBase;
  if (sh) {
    d0 = (bid & 7) * 128; m0 = (bid >> 3) * 128;
    Klen = 2048; astr = 2048; bstr = 2048;
    aBase = as_buf; bBase = wsfc2;
  } else {
    const int b2 = bid - 128;
    int lt;
    if (!resolve_tile128(cnt, b2 >> 3, e, lt)) return;
    d0 = (b2 & 7) * 128;
    rowBase = offs[e] + lt * 128;
    nrows = cnt[e] - lt * 128; if (nrows > 128) nrows = 128;
    Klen = 1024; astr = 1024; bstr = 1024;
    aBase = a_buf + (size_t)rowBase * 1024;
    bBase = wfc2 + (size_t)e * 1024 * 1024;
  }
  const int lane = tid & 63, ml = lane & 15, kq = lane >> 4, mlo = lane & 7;
  const int wv = tid >> 6, wr = wv >> 1, wc = wv & 1;
  const int lrow = lane >> 3, lchk = lane & 7;
  const short* aSrc[4]; const short* bSrc[4];
#pragma unroll
  for (int t = 0; t < 4; t++) {
    const int r = wv * 32 + t * 8 + lrow;
    const int sc = (lchk ^ (r & 7)) * 8;
    aSrc[t] = aBase + (size_t)(sh ? (m0 + r) : r) * astr + sc;
    bSrc[t] = bBase + (size_t)(d0 + r) * bstr + sc;
  }
  f32x4 acc[4][4] = {};
  for (int k0 = 0; k0 < Klen; k0 += 64) {
#pragma unroll
    for (int t = 0; t < 4; t++) gld_lds16(aSrc[t] + k0, As + (wv * 32 + t * 8) * 64);
#pragma unroll
    for (int t = 0; t < 4; t++) gld_lds16(bSrc[t] + k0, Bs + (wv * 32 + t * 8) * 64);
    __syncthreads();
#pragma unroll
    for (int kk = 0; kk < 2; kk++) {
      const int so = ((kk * 4 + kq) ^ mlo) * 8;
      bfrag af[4], bf[4];
#pragma unroll
      for (int i = 0; i < 4; i++) af[i] = *(bfrag*)&As[(wr * 64 + i * 16 + ml) * 64 + so];
#pragma unroll
      for (int j = 0; j < 4; j++) bf[j] = *(bfrag*)&Bs[(wc * 64 + j * 16 + ml) * 64 + so];
#pragma unroll
      for (int i = 0; i < 4; i++)
#pragma unroll
        for (int j = 0; j < 4; j++)
          acc[i][j] = __builtin_amdgcn_mfma_f32_16x16x32_bf16(af[i], bf[j], acc[i][j], 0, 0, 0);
    }
    __syncthreads();
  }
#pragma unroll
  for (int j = 0; j < 4; j++) {
    const int d = d0 + wc * 64 + j * 16 + ml;
    const float bv = sh ? s_b[d] : e_b[(size_t)e * 1024 + d];
#pragma unroll
    for (int i = 0; i < 4; i++)
#pragma unroll
      for (int rg = 0; rg < 4; rg++) {
        const int row = wr * 64 + i * 16 + kq * 4 + rg;
        if (sh) {
          y[(size_t)(m0 + row) * 1024 + d] = acc[i][j][rg] + bv;
        } else if (row < nrows) {
          const float wt = row_wt[rowBase + row];
          yexp[(size_t)(rowBase + row) * 1024 + d] = f2bf((acc[i][j][rg] + bv) * wt);
        }
      }
  }
}

// ---------------- combine ----------------
__global__ __launch_bounds__(256) void k_combine(float* __restrict__ y,
    const short* __restrict__ yexp, const int* __restrict__ row_id)
{
  const int idx = blockIdx.x * 256 + threadIdx.x;
  const int t = idx >> 8;
  const int d4 = (idx & 255) * 4;
  const int r0 = row_id[t * 3], r1 = row_id[t * 3 + 1], r2 = row_id[t * 3 + 2];
  float4 acc = *(float4*)(y + (size_t)t * 1024 + d4);
  const ushort4 v0 = *(const ushort4*)(yexp + (size_t)r0 * 1024 + d4);
  const ushort4 v1 = *(const ushort4*)(yexp + (size_t)r1 * 1024 + d4);
  const ushort4 v2 = *(const ushort4*)(yexp + (size_t)r2 * 1024 + d4);
  acc.x += bf2f(v0.x) + bf2f(v1.x) + bf2f(v2.x);
  acc.y += bf2f(v0.y) + bf2f(v1.y) + bf2f(v2.y);
  acc.z += bf2f(v0.z) + bf2f(v1.z) + bf2f(v2.z);
  acc.w += bf2f(v0.w) + bf2f(v1.w) + bf2f(v2.w);
  *(float4*)(y + (size_t)t * 1024 + d4) = acc;
}

extern "C" void kernel_launch(void* const* d_in, const int* in_sizes, int n_in,
                              void* d_out, int out_size, void* d_ws, size_t ws_size,
                              hipStream_t stream) {
  const float* x          = (const float*)d_in[0];
  const float* gate_w     = (const float*)d_in[1];
  const float* fc1_w      = (const float*)d_in[2];
  const float* fc1_b      = (const float*)d_in[3];
  const float* geglu_mult = (const float*)d_in[4];
  const float* fc2_w      = (const float*)d_in[5];
  const float* fc2_b      = (const float*)d_in[6];
  const float* s_fc1_w    = (const float*)d_in[7];
  const float* s_fc1_b    = (const float*)d_in[8];
  const float* s_mult     = (const float*)d_in[9];
  const float* s_fc2_w    = (const float*)d_in[10];
  const float* s_fc2_b    = (const float*)d_in[11];
  float* y = (float*)d_out;

  char* wsb = (char*)d_ws;
  int*   cnt      = (int*)(wsb + 0);
  int*   offs     = (int*)(wsb + 64);
  int*   topk_idx = (int*)(wsb + 256);
  float* topk_w   = (float*)(wsb + 24832);
  int*   row_tok  = (int*)(wsb + 49408);
  float* row_wt   = (float*)(wsb + 74496);
  int*   row_id   = (int*)(wsb + 99584);
  short* xbf      = (short*)(wsb + 131072);       // 2048x1024
  short* a_buf    = (short*)(wsb + 8519680);      // 6272x1024
  short* as_buf   = (short*)(wsb + 21364736);     // 2048x2048
  short* yexp     = (short*)(wsb + 29753344);     // 6272x1024
  short* wbf_sfc1 = (short*)(wsb + 42598400);     // 4096x1024
  short* wbf_sfc2 = (short*)(wsb + 50987008);     // 1024x2048
  short* wbf_fc1  = (short*)(wsb + 55181312);     // 15x2048x1024
  short* wbf_fc2  = (short*)(wsb + 118095872);    // 15x1024x1024
  // total ~149.6 MB

  k_convert_w<<<3264, 256, 0, stream>>>(fc1_w, fc2_w, s_fc1_w, s_fc2_w,
                                        wbf_fc1, wbf_fc2, wbf_sfc1, wbf_sfc2);
  k_gate<<<512, 64, 0, stream>>>(x, gate_w, topk_idx, topk_w, xbf);
  k_route<<<1, 1024, 0, stream>>>(topk_idx, topk_w, cnt, offs, row_tok, row_wt, row_id);
  k_fc1<<<1520, 256, 0, stream>>>(xbf, wbf_sfc1, s_fc1_b, s_mult,
                                  wbf_fc1, fc1_b, geglu_mult,
                                  cnt, offs, row_tok, as_buf, a_buf);
  k_fc2<<<632, 256, 0, stream>>>(as_buf, wbf_sfc2, s_fc2_b,
                                 a_buf, wbf_fc2, fc2_b,
                                 cnt, offs, row_wt, y, yexp);
  k_combine<<<2048, 256, 0, stream>>>(y, yexp, row_id);
}